// Round 1
// baseline (460.560 us; speedup 1.0000x reference)
//
#include <hip/hip_runtime.h>
#include <math.h>

typedef float f2 __attribute__((ext_vector_type(2)));
typedef float f2u __attribute__((ext_vector_type(2), aligned(4)));
typedef float f4 __attribute__((ext_vector_type(4)));

#define BN 8
#define CIN 3
#define HH 512
#define WW 512
#define KK 9
#define PATCH 27

// ws layout (floats):
//   [0,756)   : conv weights, row j (patch elem j = c*9 + kh*3 + kw), stride 28:
//               ws[j*28 + q] = w_off[ch(q)*27 + j]   (ch(q) invalid -> 0)
//               pair mapping ch(q): p=q>>1, h=q&1 ->
//                 p<9  : 2p+h          (offset channels, pairs (oy_k, ox_k))
//                 p>=9 : 18+2(p-9)+h   (mask channels, pairs (m0,m1)..(m8,pad))
//   [768,876) : contraction, ws[768 + k*12 + c*4 + o] = o<3 ? w_def[o*27+c*9+k] : 0
//   [880,908) : packed bias, ws[880 + q] = b_off[ch(q)]  (invalid -> 0)

__device__ __forceinline__ int pair_ch(int q) {
    const int p = q >> 1, hh = q & 1;
    return (p < 9) ? (2 * p + hh) : (18 + 2 * (p - 9) + hh);
}

__global__ void reorder_weights(const float* __restrict__ w_off,
                                const float* __restrict__ w_def,
                                const float* __restrict__ b_off,
                                float* __restrict__ ws)
{
    for (int idx = threadIdx.x; idx < 908; idx += blockDim.x) {
        float v = 0.0f;
        if (idx < 756) {
            const int j = idx / 28, q = idx % 28;
            const int ch = pair_ch(q);
            if (ch < PATCH) v = w_off[ch * PATCH + j];
        } else if (idx >= 768 && idx < 876) {
            const int r = idx - 768;
            const int k = r / 12, c = (r % 12) >> 2, o = r & 3;
            if (o < 3) v = w_def[o * PATCH + c * KK + k];
        } else if (idx >= 880) {
            const int q = idx - 880;
            const int ch = pair_ch(q);
            if (ch < PATCH) v = b_off[ch];
        }
        ws[idx] = v;
    }
}

__global__ __launch_bounds__(256) void deform_fused_kernel(
    const float* __restrict__ x,
    const float* __restrict__ wsw,    // reordered weights/bias, uniform -> s_load
    const float* __restrict__ b_def,
    float* __restrict__ out)
{
    const int w = blockIdx.x * blockDim.x + threadIdx.x;
    const int h = blockIdx.y;
    const int b = blockIdx.z;

    const size_t plane = (size_t)HH * WW;
    const float* xb = x + (size_t)b * CIN * plane;

    // ---- 3x3x3 zero-padded patch, flat index = c*9 + t ----
    float patch[PATCH];
    #pragma unroll
    for (int c = 0; c < CIN; ++c) {
        const float* xp = xb + c * plane;
        #pragma unroll
        for (int t = 0; t < KK; ++t) {
            const int yy = h + t / 3 - 1;
            const int xx = w + t % 3 - 1;
            const bool in = (yy >= 0) & (yy < HH) & (xx >= 0) & (xx < WW);
            patch[c * KK + t] = in ? xp[yy * WW + xx] : 0.0f;
        }
    }

    // ---- one-pass 27->27ch conv: 14 packed f2 accumulators (independent chains) ----
    f2 cv[14];
    #pragma unroll
    for (int p = 0; p < 14; ++p) cv[p] = *(const f2*)(wsw + 880 + 2 * p);

    #pragma unroll
    for (int j = 0; j < PATCH; ++j) {
        const f2 pp = { patch[j], patch[j] };
        const float* row = wsw + j * 28;   // uniform, contiguous 112B -> wide s_load
        #pragma unroll
        for (int p = 0; p < 14; ++p) {
            cv[p] = __builtin_elementwise_fma(*(const f2*)(row + 2 * p), pp, cv[p]);
        }
    }

    f2 acc01 = { b_def[0], b_def[1] };
    float acc2 = b_def[2];

    // ---- tap loop: bilinear sample + contraction; fully unrolled (static cv idx) ----
    #pragma unroll
    for (int k = 0; k < KK; ++k) {
        const f2 oyx = cv[k];                              // (oy_k, ox_k)
        const float om = (k & 1) ? cv[9 + (k >> 1)].y
                                 : cv[9 + (k >> 1)].x;     // mask logit
        const float m = 1.0f / (1.0f + __expf(-om));

        const float py = (float)h + (float)(k / 3 - 1) + oyx.x;
        const float px = (float)w + (float)(k % 3 - 1) + oyx.y;
        const float y0f = floorf(py);
        const float x0f = floorf(px);
        const float dy = py - y0f;
        const float dx = px - x0f;
        const int y0 = (int)y0f;
        const int x0 = (int)x0f;

        const f2 dxp = { 1.0f - dx, dx };
        const f2 wT = dxp * (1.0f - dy);   // (w00, w01)
        const f2 wB = dxp * dy;            // (w10, w11)

        const int interior = (y0 >= 0) & (y0 + 1 < HH) & (x0 >= 0) & (x0 + 1 < WW);
        const float* blkc = wsw + 768 + k * 12;

        if (__all(interior)) {
            const int idx = y0 * WW + x0;
            #pragma unroll
            for (int c = 0; c < CIN; ++c) {
                const float* xp = xb + c * plane + idx;
                const f2 vT = *(const f2u*)(xp);
                const f2 vB = *(const f2u*)(xp + WW);
                f2 s = vT * wT;
                s = __builtin_elementwise_fma(vB, wB, s);
                const float val = (s.x + s.y) * m;
                const f4 wq = *(const f4*)(blkc + 4 * c);
                const f2 w01 = { wq.x, wq.y };
                const f2 vv = { val, val };
                acc01 = __builtin_elementwise_fma(w01, vv, acc01);
                acc2 = fmaf(wq.z, val, acc2);
            }
        } else {
            const bool vy0 = (y0 >= 0)     & (y0 < HH);
            const bool vy1 = (y0 + 1 >= 0) & (y0 + 1 < HH);
            const bool vx0 = (x0 >= 0)     & (x0 < WW);
            const bool vx1 = (x0 + 1 >= 0) & (x0 + 1 < WW);

            const int yc0 = min(max(y0, 0), HH - 1);
            const int yc1 = min(max(y0 + 1, 0), HH - 1);
            const int xc0 = min(max(x0, 0), WW - 1);
            const int xc1 = min(max(x0 + 1, 0), WW - 1);

            #pragma unroll
            for (int c = 0; c < CIN; ++c) {
                const float* xp = xb + c * plane;
                const float v00 = (vy0 & vx0) ? xp[yc0 * WW + xc0] : 0.0f;
                const float v01 = (vy0 & vx1) ? xp[yc0 * WW + xc1] : 0.0f;
                const float v10 = (vy1 & vx0) ? xp[yc1 * WW + xc0] : 0.0f;
                const float v11 = (vy1 & vx1) ? xp[yc1 * WW + xc1] : 0.0f;

                const float val =
                    (v00 * wT.x + v01 * wT.y + v10 * wB.x + v11 * wB.y) * m;
                const f4 wq = *(const f4*)(blkc + 4 * c);
                const f2 w01 = { wq.x, wq.y };
                const f2 vv = { val, val };
                acc01 = __builtin_elementwise_fma(w01, vv, acc01);
                acc2 = fmaf(wq.z, val, acc2);
            }
        }
    }

    const size_t base = (size_t)b * (CIN * plane) + (size_t)h * WW + w;
    out[base]             = acc01.x;
    out[base + plane]     = acc01.y;
    out[base + 2 * plane] = acc2;
}

extern "C" void kernel_launch(void* const* d_in, const int* in_sizes, int n_in,
                              void* d_out, int out_size, void* d_ws, size_t ws_size,
                              hipStream_t stream) {
    const float* x     = (const float*)d_in[0];
    const float* w_off = (const float*)d_in[1];
    const float* b_off = (const float*)d_in[2];
    const float* w_def = (const float*)d_in[3];
    const float* b_def = (const float*)d_in[4];
    float* out = (float*)d_out;
    float* wsw = (float*)d_ws;   // 908 floats of reordered weights/bias

    reorder_weights<<<1, 256, 0, stream>>>(w_off, w_def, b_off, wsw);

    dim3 block(256, 1, 1);
    dim3 grid(WW / 256, HH, BN);  // (2, 512, 8)
    deform_fused_kernel<<<grid, block, 0, stream>>>(x, wsw, b_def, out);
}